// Round 6
// baseline (185.127 us; speedup 1.0000x reference)
//
#include <hip/hip_runtime.h>

// Longformer self-attention, MI355X gfx950. Round 6: k_lattn — QBLK=128 (2 frags/wave),
// reg-prefetch K/V pipeline (T14), XCD-grouped block order (T1). Others unchanged from R5.
// B=2 S=4096 E=768 H=12 D=64 w=256 G=64 (hardcoded to match setup_inputs()).
// Workspace requirement: ~108 MB (partials reuse the dead OFF_V region).

#define BB 2
#define SS 4096
#define EE 768
#define HH 12
#define DD 64
#define WW 256
#define GG 64
#define NSPLIT 16

typedef unsigned short u16;
typedef __attribute__((ext_vector_type(4))) float f4v;
typedef __attribute__((ext_vector_type(8))) short s8v;
typedef __attribute__((ext_vector_type(4))) int i4v;
typedef __attribute__((ext_vector_type(4))) unsigned short us4v;

#define MFMA_BF16(a, b, c) __builtin_amdgcn_mfma_f32_16x16x32_bf16((a), (b), (c), 0, 0, 0)

constexpr long NSE     = (long)BB * SS * EE;          // 6291456
constexpr long OFF_HSB = 0;
constexpr long OFF_WT  = OFF_HSB + NSE;
constexpr long OFF_Q   = OFF_WT + 6L * EE * EE;
constexpr long OFF_K   = OFF_Q + NSE;
constexpr long OFF_V   = OFF_K + NSE;                 // dead after k_vtrans -> reused for gattn partials
constexpr long OFF_KG  = OFF_V + NSE;
constexpr long OFF_VG  = OFF_KG + NSE;
constexpr long OFF_QG  = OFF_VG + NSE;
constexpr long OFF_VT  = OFF_QG + (long)BB * GG * EE;
constexpr long OFF_VGT = OFF_VT + NSE;                // end = 53968896 elems = ~108 MB

constexpr long NQTILE = (long)BB * HH * 4;            // 96 global-q subtiles of 16 rows

__device__ __forceinline__ u16 f2bf(float f) {
  unsigned u = __float_as_uint(f);
  u += 0x7fffu + ((u >> 16) & 1u);   // RNE
  return (u16)(u >> 16);
}

__device__ __forceinline__ void gload_lds16(const u16* g, u16* l) {
  __builtin_amdgcn_global_load_lds(
      (const __attribute__((address_space(1))) void*)g,
      (__attribute__((address_space(3))) void*)l, 16, 0, 0);
}

// ---------------- cast hidden_states f32 -> bf16 ----------------
__global__ void k_cast(const float* __restrict__ hs, u16* __restrict__ hsb) {
  long i = ((long)blockIdx.x * 256 + threadIdx.x) * 4;
  f4v v = *(const f4v*)(hs + i);
  us4v o;
#pragma unroll
  for (int j = 0; j < 4; ++j) o[j] = f2bf(v[j]);
  *(us4v*)(hsb + i) = o;
}

// ---------------- transpose+cast weights: Wt[widx][n][k] = W[k][n] ----------------
__global__ __launch_bounds__(256) void k_wtrans(const float* __restrict__ Wq, const float* __restrict__ Wk,
                                                const float* __restrict__ Wv, const float* __restrict__ Wkg,
                                                const float* __restrict__ Wvg, const float* __restrict__ Wqg,
                                                u16* __restrict__ Wt) {
  int bid = blockIdx.x;
  int widx = bid / 576; int rem = bid % 576; int kt = rem / 24; int nt = rem % 24;
  const float* src;
  switch (widx) {
    case 0: src = Wq; break; case 1: src = Wk; break; case 2: src = Wv; break;
    case 3: src = Wkg; break; case 4: src = Wvg; break; default: src = Wqg; break;
  }
  __shared__ float tl[32][33];
  int t = threadIdx.x; int r = t >> 3; int c4 = (t & 7) * 4;
  f4v v = *(const f4v*)(src + (long)(kt * 32 + r) * EE + nt * 32 + c4);
#pragma unroll
  for (int j = 0; j < 4; ++j) tl[r][c4 + j] = v[j];
  __syncthreads();
  us4v o;
#pragma unroll
  for (int j = 0; j < 4; ++j) o[j] = f2bf(tl[c4 + j][r]);
  *(us4v*)(Wt + (long)widx * EE * EE + (long)(nt * 32 + r) * EE + kt * 32 + c4) = o;
}

// ---------------- projection GEMM: out = hs @ W + b (bf16 MFMA, 128x128 tile, BK=64) ----------------
__global__ __launch_bounds__(256, 4) void k_proj(u16* __restrict__ ws,
                                              const float* __restrict__ bq, const float* __restrict__ bk,
                                              const float* __restrict__ bv, const float* __restrict__ bkg,
                                              const float* __restrict__ bvg, const float* __restrict__ bqg) {
  int bid = blockIdx.x;
  int widx, mt, nt;
  if (bid < 1920) {
    int L = (bid & 7) * 240 + (bid >> 3);   // bijective XCD swizzle (1920 % 8 == 0)
    mt = L / 30; int inner = L % 30; widx = inner / 6; nt = inner % 6;
  } else { widx = 5; mt = 0; nt = bid - 1920; }

  __shared__ u16 Al[128 * 64];
  __shared__ u16 Bl[128 * 64];
  int tid = threadIdx.x, lane = tid & 63, wid = tid >> 6;
  int wr = wid >> 1, wc = wid & 1;

  f4v acc[4][4];
#pragma unroll
  for (int i = 0; i < 4; ++i)
#pragma unroll
    for (int j = 0; j < 4; ++j) acc[i][j] = f4v{0.f, 0.f, 0.f, 0.f};

  const u16* hsb = ws + OFF_HSB;
  const u16* Wp  = ws + OFF_WT + (long)widx * EE * EE;

  const u16* asrc[4]; const u16* bsrc[4];
  u16* adst[4]; u16* bdst[4];
#pragma unroll
  for (int it = 0; it < 4; ++it) {
    int c = tid + it * 256;
    int r = c >> 3, o8 = (c & 7) * 8;
    long arow;
    if (widx == 5) { int rr = mt * 128 + r; arow = (long)(rr >> 6) * SS + (rr & 63); }
    else           { arow = (long)mt * 128 + r; }
    asrc[it] = hsb + arow * EE + o8;
    bsrc[it] = Wp + (long)(nt * 128 + r) * EE + o8;
    adst[it] = Al + c * 8;
    bdst[it] = Bl + c * 8;
  }

  const u16* afp[4]; const u16* bfp[4];
#pragma unroll
  for (int f = 0; f < 4; ++f) {
    afp[f] = Al + (wr * 64 + f * 16 + (lane & 15)) * 64 + (lane >> 4) * 8;
    bfp[f] = Bl + (wc * 64 + f * 16 + (lane & 15)) * 64 + (lane >> 4) * 8;
  }

  for (int k0 = 0; k0 < EE; k0 += 64) {
#pragma unroll
    for (int it = 0; it < 4; ++it) {
      gload_lds16(asrc[it] + k0, adst[it]);
      gload_lds16(bsrc[it] + k0, bdst[it]);
    }
    __syncthreads();
#pragma unroll
    for (int ks = 0; ks < 2; ++ks) {
      s8v af[4], bfr[4];
#pragma unroll
      for (int f = 0; f < 4; ++f) {
        af[f]  = *(const s8v*)(afp[f] + ks * 32);
        bfr[f] = *(const s8v*)(bfp[f] + ks * 32);
      }
#pragma unroll
      for (int i = 0; i < 4; ++i)
#pragma unroll
        for (int j = 0; j < 4; ++j) acc[i][j] = MFMA_BF16(af[i], bfr[j], acc[i][j]);
    }
    __syncthreads();
  }

  const float* bias; u16* outp; float scl = 1.0f;
  switch (widx) {
    case 0: bias = bq;  outp = ws + OFF_Q;  scl = 0.125f; break;
    case 1: bias = bk;  outp = ws + OFF_K;  break;
    case 2: bias = bv;  outp = ws + OFF_V;  break;
    case 3: bias = bkg; outp = ws + OFF_KG; break;
    case 4: bias = bvg; outp = ws + OFF_VG; break;
    default: bias = bqg; outp = ws + OFF_QG; scl = 0.125f; break;
  }
#pragma unroll
  for (int fi = 0; fi < 4; ++fi)
#pragma unroll
    for (int fj = 0; fj < 4; ++fj) {
      int col = nt * 128 + wc * 64 + fj * 16 + (lane & 15);
      float bcol = bias[col];
#pragma unroll
      for (int e = 0; e < 4; ++e) {
        int rl = wr * 64 + fi * 16 + (lane >> 4) * 4 + e;
        float vv = (acc[fi][fj][e] + bcol) * scl;
        outp[(long)(mt * 128 + rl) * EE + col] = f2bf(vv);
      }
    }
}

// ---------------- transpose V/Vg -> Vt/Vgt: Vt[(b*H+h)*64+d][s] = V[b][s][h*64+d] ----------------
__global__ __launch_bounds__(256) void k_vtrans(u16* __restrict__ ws) {
  int bid = blockIdx.x;
  int arr = bid / 6144; int rem = bid % 6144;
  int st = rem % 128; int combo = rem / 128;
  int b = combo / 24; int r2 = combo % 24; int h = r2 >> 1; int d0 = (r2 & 1) * 32;
  const u16* src = ws + (arr ? OFF_VG : OFF_V);
  u16* dst = ws + (arr ? OFF_VGT : OFF_VT);
  __shared__ u16 tl[32][36];
  int t = threadIdx.x;
  int r = t >> 3; int c4 = (t & 7) * 4;
  us4v v = *(const us4v*)(src + (long)(b * SS + st * 32 + r) * EE + h * DD + d0 + c4);
#pragma unroll
  for (int j = 0; j < 4; ++j) tl[r][c4 + j] = v[j];
  __syncthreads();
  int dloc = t >> 3; int s4 = (t & 7) * 4;
  us4v o;
#pragma unroll
  for (int j = 0; j < 4; ++j) o[j] = tl[s4 + j][dloc];
  *(us4v*)(dst + (long)((b * HH + h) * DD + d0 + dloc) * SS + st * 32 + s4) = o;
}

// ---------------- local (band + global-key) attention, rows >= G ----------------
// QBLK=128: 4 waves x 32 q-rows (2 16-row frags); tail block (qt=31) runs 64 rows, 1 frag.
// KVBLK=64, defer-max (THR=8), reg-prefetch K/V pipeline, XCD-grouped block order.
__global__ __launch_bounds__(256) void k_lattn(const u16* __restrict__ ws, float* __restrict__ out) {
  int bid0 = blockIdx.x;
  int bid = (bid0 & 7) * 96 + (bid0 >> 3);          // 768 blocks, qt-contiguous per XCD
  int b = bid / (HH * 32); int rem = bid % (HH * 32); int h = rem / 32; int qt = rem % 32;
  int l0 = GG + qt * 128;
  int nfrag = (qt == 31) ? 1 : 2;                   // rows = nfrag * 64
  int rows = nfrag * 64;
  int tid = threadIdx.x, lane = tid & 63, wid = tid >> 6;

  __shared__ u16 Kl[64][72];
  __shared__ u16 Vtl[64][72];
  __shared__ u16 Pl[4][32][72];

  const u16* Qp  = ws + OFF_Q + (long)b * SS * EE;
  const u16* Kp  = ws + OFF_K + (long)b * SS * EE;
  const u16* Vtp = ws + OFF_VT + (long)(b * HH + h) * DD * SS;

  int qbase = l0 + wid * (nfrag * 16);
  s8v qf[2][2];
#pragma unroll
  for (int f = 0; f < 2; ++f)
    if (f < nfrag)
#pragma unroll
      for (int ks = 0; ks < 2; ++ks)
        qf[f][ks] = *(const s8v*)(Qp + (long)(qbase + f * 16 + (lane & 15)) * EE + h * DD + ks * 32 + (lane >> 4) * 8);

  float m_r[2][4], l_r[2][4]; f4v ao[2][4];
#pragma unroll
  for (int f = 0; f < 2; ++f)
#pragma unroll
    for (int e = 0; e < 4; ++e) { m_r[f][e] = -1e30f; l_r[f][e] = 0.f; }
#pragma unroll
  for (int f = 0; f < 2; ++f)
#pragma unroll
    for (int df = 0; df < 4; ++df) ao[f][df] = f4v{0.f, 0.f, 0.f, 0.f};

  int lo = (l0 - WW > GG) ? (l0 - WW) : GG;
  int hi = (l0 + rows + WW < SS) ? (l0 + rows + WW) : SS;
  int ntile = 1 + ((hi - lo) >> 6);

  // staging geometry: K tile 64x64 bf16 = 512 16B-chunks; thread handles 2 K + 2 V chunks
  int sr[2], so[2];
  const u16* kbase[2]; const u16* vbase[2];
  u16* kdst[2]; u16* vdst[2];
#pragma unroll
  for (int it = 0; it < 2; ++it) {
    int c = tid + it * 256;
    sr[it] = c >> 3; so[it] = (c & 7) * 8;
    kbase[it] = Kp + (long)sr[it] * EE + h * DD + so[it];
    vbase[it] = Vtp + (long)sr[it] * SS + so[it];
    kdst[it] = &Kl[sr[it]][so[it]];
    vdst[it] = &Vtl[sr[it]][so[it]];
  }

  // prologue: stage tile 0 (global keys, kb=0)
  i4v kreg[2], vreg[2];
#pragma unroll
  for (int it = 0; it < 2; ++it) {
    kreg[it] = *(const i4v*)(kbase[it]);
    vreg[it] = *(const i4v*)(vbase[it]);
  }
#pragma unroll
  for (int it = 0; it < 2; ++it) {
    *(i4v*)kdst[it] = kreg[it];
    *(i4v*)vdst[it] = vreg[it];
  }
  __syncthreads();

  for (int t = 0; t < ntile; ++t) {
    int kb = (t == 0) ? 0 : lo + (t - 1) * 64;
    // prefetch next tile into regs (latency hides under compute below)
    if (t + 1 < ntile) {
      int kbn = lo + t * 64;
#pragma unroll
      for (int it = 0; it < 2; ++it) {
        kreg[it] = *(const i4v*)(kbase[it] + (long)kbn * EE);
        vreg[it] = *(const i4v*)(vbase[it] + kbn);
      }
    }

    // QK^T: K-frag read once, shared by both q-frags
    f4v sc[2][4];
#pragma unroll
    for (int f = 0; f < 2; ++f)
#pragma unroll
      for (int c = 0; c < 4; ++c) sc[f][c] = f4v{0.f, 0.f, 0.f, 0.f};
#pragma unroll
    for (int c = 0; c < 4; ++c)
#pragma unroll
      for (int ks = 0; ks < 2; ++ks) {
        s8v kf = *(const s8v*)&Kl[c * 16 + (lane & 15)][ks * 32 + (lane >> 4) * 8];
        sc[0][c] = MFMA_BF16(qf[0][ks], kf, sc[0][c]);
        if (nfrag == 2) sc[1][c] = MFMA_BF16(qf[1][ks], kf, sc[1][c]);
      }

    // window mask: needed only for kb <= l0-192 or kb >= l0+256 (conservative for tail)
    if (t > 0 && (kb <= l0 - 192 || kb >= l0 + WW)) {
#pragma unroll
      for (int f = 0; f < 2; ++f) {
        if (f >= nfrag) break;
#pragma unroll
        for (int c = 0; c < 4; ++c) {
          int key = kb + c * 16 + (lane & 15);
#pragma unroll
          for (int e = 0; e < 4; ++e) {
            int qrow = qbase + f * 16 + (lane >> 4) * 4 + e;
            if (key < qrow - WW || key > qrow + WW) sc[f][c][e] = -1e30f;
          }
        }
      }
    }

    // defer-max (THR=8)
    float pmax[2][4];
#pragma unroll
    for (int f = 0; f < 2; ++f)
      if (f < nfrag)
#pragma unroll
        for (int e = 0; e < 4; ++e)
          pmax[f][e] = fmaxf(fmaxf(sc[f][0][e], sc[f][1][e]), fmaxf(sc[f][2][e], sc[f][3][e]));
    bool need;
    if (t == 0) need = true;
    else {
      bool ok = true;
#pragma unroll
      for (int f = 0; f < 2; ++f)
        if (f < nfrag)
#pragma unroll
          for (int e = 0; e < 4; ++e) ok &= (pmax[f][e] <= m_r[f][e] + 8.f);
      need = !__all(ok);
    }
    if (need) {
#pragma unroll
      for (int f = 0; f < 2; ++f) {
        if (f >= nfrag) break;
#pragma unroll
        for (int e = 0; e < 4; ++e) {
          float rm = pmax[f][e];
#pragma unroll
          for (int off = 1; off < 16; off <<= 1) rm = fmaxf(rm, __shfl_xor(rm, off));
          float mn = fmaxf(m_r[f][e], rm);
          float scl = __expf(m_r[f][e] - mn);
          l_r[f][e] *= scl;
#pragma unroll
          for (int df = 0; df < 4; ++df) ao[f][df][e] *= scl;
          m_r[f][e] = mn;
        }
      }
    }

    // probabilities + row-sum + P store (bf16)
#pragma unroll
    for (int f = 0; f < 2; ++f) {
      if (f >= nfrag) break;
#pragma unroll
      for (int e = 0; e < 4; ++e) {
        float p0 = __expf(sc[f][0][e] - m_r[f][e]);
        float p1 = __expf(sc[f][1][e] - m_r[f][e]);
        float p2 = __expf(sc[f][2][e] - m_r[f][e]);
        float p3 = __expf(sc[f][3][e] - m_r[f][e]);
        float s = (p0 + p1) + (p2 + p3);
#pragma unroll
        for (int off = 1; off < 16; off <<= 1) s += __shfl_xor(s, off);
        l_r[f][e] += s;
        int pr = f * 16 + (lane >> 4) * 4 + e;
        Pl[wid][pr][(lane & 15)]      = f2bf(p0);
        Pl[wid][pr][16 + (lane & 15)] = f2bf(p1);
        Pl[wid][pr][32 + (lane & 15)] = f2bf(p2);
        Pl[wid][pr][48 + (lane & 15)] = f2bf(p3);
      }
    }

    // PV: V-frag read once, shared by both q-frags
#pragma unroll
    for (int kblk = 0; kblk < 2; ++kblk) {
      s8v pf0 = *(const s8v*)&Pl[wid][(lane & 15)][kblk * 32 + (lane >> 4) * 8];
      s8v pf1;
      if (nfrag == 2) pf1 = *(const s8v*)&Pl[wid][16 + (lane & 15)][kblk * 32 + (lane >> 4) * 8];
#pragma unroll
      for (int df = 0; df < 4; ++df) {
        s8v vf = *(const s8v*)&Vtl[df * 16 + (lane & 15)][kblk * 32 + (lane >> 4) * 8];
        ao[0][df] = MFMA_BF16(pf0, vf, ao[0][df]);
        if (nfrag == 2) ao[1][df] = MFMA_BF16(pf1, vf, ao[1][df]);
      }
    }
    __syncthreads();   // all waves done reading Kl/Vtl

    if (t + 1 < ntile) {
#pragma unroll
      for (int it = 0; it < 2; ++it) {
        *(i4v*)kdst[it] = kreg[it];
        *(i4v*)vdst[it] = vreg[it];
      }
    }
    __syncthreads();   // staged tile visible
  }

#pragma unroll
  for (int f = 0; f < 2; ++f) {
    if (f >= nfrag) break;
#pragma unroll
    for (int df = 0; df < 4; ++df)
#pragma unroll
      for (int e = 0; e < 4; ++e) {
        int row = qbase + f * 16 + (lane >> 4) * 4 + e;
        int col = h * DD + df * 16 + (lane & 15);
        out[((long)b * SS + row) * EE + col] = ao[f][df][e] / l_r[f][e];
      }
  }
}

// ---------------- global attention, rows < G: split-K partials ----------------
__global__ __launch_bounds__(64) void k_gattn_part(u16* __restrict__ ws) {
  int bid = blockIdx.x;
  int g = bid / NSPLIT; int sp = bid % NSPLIT;
  int b = g / (HH * 4); int rem = g % (HH * 4); int h = rem >> 2; int qs = rem & 3;
  int lane = threadIdx.x;

  __shared__ u16 Kl[32][72];
  __shared__ u16 Vtl[64][40];
  __shared__ u16 Pl[16][40];

  const u16* Qgp = ws + OFF_QG + (long)b * GG * EE;
  const u16* Kgp = ws + OFF_KG + (long)b * SS * EE;
  const u16* Vtp = ws + OFF_VGT + (long)(b * HH + h) * DD * SS;

  int qbase = qs * 16;
  s8v qf[2];
#pragma unroll
  for (int ks = 0; ks < 2; ++ks)
    qf[ks] = *(const s8v*)(Qgp + (long)(qbase + (lane & 15)) * EE + h * DD + ks * 32 + (lane >> 4) * 8);

  float m_r[4], l_r[4]; f4v ao[4];
#pragma unroll
  for (int e = 0; e < 4; ++e) { m_r[e] = -1e30f; l_r[e] = 0.f; }
#pragma unroll
  for (int df = 0; df < 4; ++df) ao[df] = f4v{0.f, 0.f, 0.f, 0.f};

  int t0 = sp * (SS / 32 / NSPLIT);
  for (int kt = t0; kt < t0 + SS / 32 / NSPLIT; ++kt) {
    int kb = kt * 32;
#pragma unroll
    for (int r2 = 0; r2 < 4; ++r2) {
      int chunk = lane + r2 * 64;
      int kr = chunk >> 3, ko = (chunk & 7) * 8;
      *(i4v*)&Kl[kr][ko] = *(const i4v*)(Kgp + (long)(kb + kr) * EE + h * DD + ko);
      int dr = chunk >> 2, ko2 = (chunk & 3) * 8;
      *(i4v*)&Vtl[dr][ko2] = *(const i4v*)(Vtp + (long)dr * SS + kb + ko2);
    }
    __syncthreads();

    f4v sc[2] = {f4v{0.f, 0.f, 0.f, 0.f}, f4v{0.f, 0.f, 0.f, 0.f}};
#pragma unroll
    for (int c = 0; c < 2; ++c)
#pragma unroll
      for (int ks = 0; ks < 2; ++ks) {
        s8v kf = *(const s8v*)&Kl[c * 16 + (lane & 15)][ks * 32 + (lane >> 4) * 8];
        sc[c] = MFMA_BF16(qf[ks], kf, sc[c]);
      }

    float scl_[4], p0[4], p1[4];
#pragma unroll
    for (int e = 0; e < 4; ++e) {
      float rm = fmaxf(sc[0][e], sc[1][e]);
#pragma unroll
      for (int off = 1; off < 16; off <<= 1) rm = fmaxf(rm, __shfl_xor(rm, off));
      float mn = fmaxf(m_r[e], rm);
      scl_[e] = __expf(m_r[e] - mn);
      p0[e] = __expf(sc[0][e] - mn);
      p1[e] = __expf(sc[1][e] - mn);
      float s = p0[e] + p1[e];
#pragma unroll
      for (int off = 1; off < 16; off <<= 1) s += __shfl_xor(s, off);
      l_r[e] = l_r[e] * scl_[e] + s;
      m_r[e] = mn;
    }
#pragma unroll
    for (int df = 0; df < 4; ++df)
#pragma unroll
      for (int e = 0; e < 4; ++e) ao[df][e] *= scl_[e];

#pragma unroll
    for (int e = 0; e < 4; ++e) {
      Pl[(lane >> 4) * 4 + e][lane & 15]        = f2bf(p0[e]);
      Pl[(lane >> 4) * 4 + e][16 + (lane & 15)] = f2bf(p1[e]);
    }
    s8v pf = *(const s8v*)&Pl[lane & 15][(lane >> 4) * 8];
#pragma unroll
    for (int df = 0; df < 4; ++df) {
      s8v vf = *(const s8v*)&Vtl[df * 16 + (lane & 15)][(lane >> 4) * 8];
      ao[df] = MFMA_BF16(pf, vf, ao[df]);
    }
    __syncthreads();
  }

  float* PA = (float*)(ws + OFF_V);
  float* Pm = PA + NQTILE * NSPLIT * 1024L;
  float* Pl2 = Pm + NQTILE * NSPLIT * 16L;
  long pb = (long)g * NSPLIT + sp;
#pragma unroll
  for (int df = 0; df < 4; ++df)
#pragma unroll
    for (int e = 0; e < 4; ++e) {
      int rl = (lane >> 4) * 4 + e;
      PA[pb * 1024 + rl * 64 + df * 16 + (lane & 15)] = ao[df][e];
    }
  if ((lane & 15) == 0) {
#pragma unroll
    for (int e = 0; e < 4; ++e) {
      int rl = (lane >> 4) * 4 + e;
      Pm[pb * 16 + rl] = m_r[e];
      Pl2[pb * 16 + rl] = l_r[e];
    }
  }
}

// ---------------- global attention: combine partials ----------------
__global__ __launch_bounds__(256) void k_gattn_comb(const u16* __restrict__ ws, float* __restrict__ out) {
  int g = blockIdx.x;
  int b = g / (HH * 4); int rem = g % (HH * 4); int h = rem >> 2; int qs = rem & 3;
  int tid = threadIdx.x;
  int row = tid >> 4; int c4 = (tid & 15) * 4;

  const float* PA = (const float*)(ws + OFF_V);
  const float* Pm = PA + NQTILE * NSPLIT * 1024L;
  const float* Pl2 = Pm + NQTILE * NSPLIT * 16L;
  long base = (long)g * NSPLIT;

  float M = -1e30f;
#pragma unroll
  for (int s = 0; s < NSPLIT; ++s) M = fmaxf(M, Pm[(base + s) * 16 + row]);
  f4v acc = f4v{0.f, 0.f, 0.f, 0.f};
  float L = 0.f;
#pragma unroll
  for (int s = 0; s < NSPLIT; ++s) {
    float wgt = __expf(Pm[(base + s) * 16 + row] - M);
    L += wgt * Pl2[(base + s) * 16 + row];
    f4v a = *(const f4v*)&PA[(base + s) * 1024 + row * 64 + c4];
#pragma unroll
    for (int j = 0; j < 4; ++j) acc[j] += wgt * a[j];
  }
  float inv = 1.f / L;
  f4v o;
#pragma unroll
  for (int j = 0; j < 4; ++j) o[j] = acc[j] * inv;
  *(f4v*)&out[((long)b * SS + qs * 16 + row) * EE + h * DD + c4] = o;
}

extern "C" void kernel_launch(void* const* d_in, const int* in_sizes, int n_in,
                              void* d_out, int out_size, void* d_ws, size_t ws_size,
                              hipStream_t stream) {
  const float* hs  = (const float*)d_in[0];
  const float* Wq  = (const float*)d_in[2];  const float* bq  = (const float*)d_in[3];
  const float* Wk  = (const float*)d_in[4];  const float* bk  = (const float*)d_in[5];
  const float* Wv  = (const float*)d_in[6];  const float* bv  = (const float*)d_in[7];
  const float* Wqg = (const float*)d_in[8];  const float* bqg = (const float*)d_in[9];
  const float* Wkg = (const float*)d_in[10]; const float* bkg = (const float*)d_in[11];
  const float* Wvg = (const float*)d_in[12]; const float* bvg = (const float*)d_in[13];
  u16* ws = (u16*)d_ws;
  float* out = (float*)d_out;

  k_cast<<<(int)(NSE / (256 * 4)), 256, 0, stream>>>(hs, ws + OFF_HSB);
  k_wtrans<<<6 * 24 * 24, 256, 0, stream>>>(Wq, Wk, Wv, Wkg, Wvg, Wqg, ws + OFF_WT);
  k_proj<<<1926, 256, 0, stream>>>(ws, bq, bk, bv, bkg, bvg, bqg);
  k_vtrans<<<2 * 6144, 256, 0, stream>>>(ws);
  k_gattn_part<<<(int)(NQTILE * NSPLIT), 64, 0, stream>>>(ws);
  k_gattn_comb<<<(int)NQTILE, 256, 0, stream>>>(ws, out);
  k_lattn<<<BB * HH * 32, 256, 0, stream>>>(ws, out);
}

// Round 7
// 160.380 us; speedup vs baseline: 1.1543x; 1.1543x over previous
//
#include <hip/hip_runtime.h>
#include <hip/hip_bf16.h>

// Longformer self-attention, MI355X gfx950. Round 7: k_lattn — revert QBLK to 64
// (R6's 128 halved parallelism: latency-bound, not BW-bound), keep reg-prefetch +
// XCD swizzle (1512=8*189), per-lane deferred l-sum (end-of-kernel reduce).
// B=2 S=4096 E=768 H=12 D=64 w=256 G=64 (hardcoded to match setup_inputs()).
// Workspace requirement: ~108 MB (partials reuse the dead OFF_V region).

#define BB 2
#define SS 4096
#define EE 768
#define HH 12
#define DD 64
#define WW 256
#define GG 64
#define NSPLIT 16

typedef unsigned short u16;
typedef __attribute__((ext_vector_type(4))) float f4v;
typedef __attribute__((ext_vector_type(8))) short s8v;
typedef __attribute__((ext_vector_type(4))) int i4v;
typedef __attribute__((ext_vector_type(4))) unsigned short us4v;

#define MFMA_BF16(a, b, c) __builtin_amdgcn_mfma_f32_16x16x32_bf16((a), (b), (c), 0, 0, 0)

constexpr long NSE     = (long)BB * SS * EE;          // 6291456
constexpr long OFF_HSB = 0;
constexpr long OFF_WT  = OFF_HSB + NSE;
constexpr long OFF_Q   = OFF_WT + 6L * EE * EE;
constexpr long OFF_K   = OFF_Q + NSE;
constexpr long OFF_V   = OFF_K + NSE;                 // dead after k_vtrans -> reused for gattn partials
constexpr long OFF_KG  = OFF_V + NSE;
constexpr long OFF_VG  = OFF_KG + NSE;
constexpr long OFF_QG  = OFF_VG + NSE;
constexpr long OFF_VT  = OFF_QG + (long)BB * GG * EE;
constexpr long OFF_VGT = OFF_VT + NSE;                // end = 53968896 elems = ~108 MB

constexpr long NQTILE = (long)BB * HH * 4;            // 96 global-q subtiles of 16 rows

__device__ __forceinline__ u16 f2bf(float f) {
  unsigned u = __float_as_uint(f);
  u += 0x7fffu + ((u >> 16) & 1u);   // RNE
  return (u16)(u >> 16);
}

__device__ __forceinline__ void gload_lds16(const u16* g, u16* l) {
  __builtin_amdgcn_global_load_lds(
      (const __attribute__((address_space(1))) void*)g,
      (__attribute__((address_space(3))) void*)l, 16, 0, 0);
}

// ---------------- cast hidden_states f32 -> bf16 ----------------
__global__ void k_cast(const float* __restrict__ hs, u16* __restrict__ hsb) {
  long i = ((long)blockIdx.x * 256 + threadIdx.x) * 4;
  f4v v = *(const f4v*)(hs + i);
  us4v o;
#pragma unroll
  for (int j = 0; j < 4; ++j) o[j] = f2bf(v[j]);
  *(us4v*)(hsb + i) = o;
}

// ---------------- transpose+cast weights: Wt[widx][n][k] = W[k][n] ----------------
__global__ __launch_bounds__(256) void k_wtrans(const float* __restrict__ Wq, const float* __restrict__ Wk,
                                                const float* __restrict__ Wv, const float* __restrict__ Wkg,
                                                const float* __restrict__ Wvg, const float* __restrict__ Wqg,
                                                u16* __restrict__ Wt) {
  int bid = blockIdx.x;
  int widx = bid / 576; int rem = bid % 576; int kt = rem / 24; int nt = rem % 24;
  const float* src;
  switch (widx) {
    case 0: src = Wq; break; case 1: src = Wk; break; case 2: src = Wv; break;
    case 3: src = Wkg; break; case 4: src = Wvg; break; default: src = Wqg; break;
  }
  __shared__ float tl[32][33];
  int t = threadIdx.x; int r = t >> 3; int c4 = (t & 7) * 4;
  f4v v = *(const f4v*)(src + (long)(kt * 32 + r) * EE + nt * 32 + c4);
#pragma unroll
  for (int j = 0; j < 4; ++j) tl[r][c4 + j] = v[j];
  __syncthreads();
  us4v o;
#pragma unroll
  for (int j = 0; j < 4; ++j) o[j] = f2bf(tl[c4 + j][r]);
  *(us4v*)(Wt + (long)widx * EE * EE + (long)(nt * 32 + r) * EE + kt * 32 + c4) = o;
}

// ---------------- projection GEMM: out = hs @ W + b (bf16 MFMA, 128x128 tile, BK=64) ----------------
__global__ __launch_bounds__(256, 4) void k_proj(u16* __restrict__ ws,
                                              const float* __restrict__ bq, const float* __restrict__ bk,
                                              const float* __restrict__ bv, const float* __restrict__ bkg,
                                              const float* __restrict__ bvg, const float* __restrict__ bqg) {
  int bid = blockIdx.x;
  int widx, mt, nt;
  if (bid < 1920) {
    int L = (bid & 7) * 240 + (bid >> 3);   // bijective XCD swizzle (1920 % 8 == 0)
    mt = L / 30; int inner = L % 30; widx = inner / 6; nt = inner % 6;
  } else { widx = 5; mt = 0; nt = bid - 1920; }

  __shared__ u16 Al[128 * 64];
  __shared__ u16 Bl[128 * 64];
  int tid = threadIdx.x, lane = tid & 63, wid = tid >> 6;
  int wr = wid >> 1, wc = wid & 1;

  f4v acc[4][4];
#pragma unroll
  for (int i = 0; i < 4; ++i)
#pragma unroll
    for (int j = 0; j < 4; ++j) acc[i][j] = f4v{0.f, 0.f, 0.f, 0.f};

  const u16* hsb = ws + OFF_HSB;
  const u16* Wp  = ws + OFF_WT + (long)widx * EE * EE;

  const u16* asrc[4]; const u16* bsrc[4];
  u16* adst[4]; u16* bdst[4];
#pragma unroll
  for (int it = 0; it < 4; ++it) {
    int c = tid + it * 256;
    int r = c >> 3, o8 = (c & 7) * 8;
    long arow;
    if (widx == 5) { int rr = mt * 128 + r; arow = (long)(rr >> 6) * SS + (rr & 63); }
    else           { arow = (long)mt * 128 + r; }
    asrc[it] = hsb + arow * EE + o8;
    bsrc[it] = Wp + (long)(nt * 128 + r) * EE + o8;
    adst[it] = Al + c * 8;
    bdst[it] = Bl + c * 8;
  }

  const u16* afp[4]; const u16* bfp[4];
#pragma unroll
  for (int f = 0; f < 4; ++f) {
    afp[f] = Al + (wr * 64 + f * 16 + (lane & 15)) * 64 + (lane >> 4) * 8;
    bfp[f] = Bl + (wc * 64 + f * 16 + (lane & 15)) * 64 + (lane >> 4) * 8;
  }

  for (int k0 = 0; k0 < EE; k0 += 64) {
#pragma unroll
    for (int it = 0; it < 4; ++it) {
      gload_lds16(asrc[it] + k0, adst[it]);
      gload_lds16(bsrc[it] + k0, bdst[it]);
    }
    __syncthreads();
#pragma unroll
    for (int ks = 0; ks < 2; ++ks) {
      s8v af[4], bfr[4];
#pragma unroll
      for (int f = 0; f < 4; ++f) {
        af[f]  = *(const s8v*)(afp[f] + ks * 32);
        bfr[f] = *(const s8v*)(bfp[f] + ks * 32);
      }
#pragma unroll
      for (int i = 0; i < 4; ++i)
#pragma unroll
        for (int j = 0; j < 4; ++j) acc[i][j] = MFMA_BF16(af[i], bfr[j], acc[i][j]);
    }
    __syncthreads();
  }

  const float* bias; u16* outp; float scl = 1.0f;
  switch (widx) {
    case 0: bias = bq;  outp = ws + OFF_Q;  scl = 0.125f; break;
    case 1: bias = bk;  outp = ws + OFF_K;  break;
    case 2: bias = bv;  outp = ws + OFF_V;  break;
    case 3: bias = bkg; outp = ws + OFF_KG; break;
    case 4: bias = bvg; outp = ws + OFF_VG; break;
    default: bias = bqg; outp = ws + OFF_QG; scl = 0.125f; break;
  }
#pragma unroll
  for (int fi = 0; fi < 4; ++fi)
#pragma unroll
    for (int fj = 0; fj < 4; ++fj) {
      int col = nt * 128 + wc * 64 + fj * 16 + (lane & 15);
      float bcol = bias[col];
#pragma unroll
      for (int e = 0; e < 4; ++e) {
        int rl = wr * 64 + fi * 16 + (lane >> 4) * 4 + e;
        float vv = (acc[fi][fj][e] + bcol) * scl;
        outp[(long)(mt * 128 + rl) * EE + col] = f2bf(vv);
      }
    }
}

// ---------------- transpose V/Vg -> Vt/Vgt: Vt[(b*H+h)*64+d][s] = V[b][s][h*64+d] ----------------
__global__ __launch_bounds__(256) void k_vtrans(u16* __restrict__ ws) {
  int bid = blockIdx.x;
  int arr = bid / 6144; int rem = bid % 6144;
  int st = rem % 128; int combo = rem / 128;
  int b = combo / 24; int r2 = combo % 24; int h = r2 >> 1; int d0 = (r2 & 1) * 32;
  const u16* src = ws + (arr ? OFF_VG : OFF_V);
  u16* dst = ws + (arr ? OFF_VGT : OFF_VT);
  __shared__ u16 tl[32][36];
  int t = threadIdx.x;
  int r = t >> 3; int c4 = (t & 7) * 4;
  us4v v = *(const us4v*)(src + (long)(b * SS + st * 32 + r) * EE + h * DD + d0 + c4);
#pragma unroll
  for (int j = 0; j < 4; ++j) tl[r][c4 + j] = v[j];
  __syncthreads();
  int dloc = t >> 3; int s4 = (t & 7) * 4;
  us4v o;
#pragma unroll
  for (int j = 0; j < 4; ++j) o[j] = tl[s4 + j][dloc];
  *(us4v*)(dst + (long)((b * HH + h) * DD + d0 + dloc) * SS + st * 32 + s4) = o;
}

// ---------------- local (band + global-key) attention, rows >= G ----------------
// 4 waves x 16 q-rows = 64 q-rows per block; KVBLK=64; defer-max (THR=8);
// reg-prefetch K/V pipeline; XCD-grouped block order (1512 = 8*189);
// per-lane deferred l-sum (single cross-lane reduce at kernel end).
__global__ __launch_bounds__(256) void k_lattn(const u16* __restrict__ ws, float* __restrict__ out) {
  int bid0 = blockIdx.x;
  int bid = (bid0 & 7) * 189 + (bid0 >> 3);         // bijective XCD swizzle
  int b = bid / (HH * 63); int rem = bid % (HH * 63); int h = rem / 63; int qt = rem % 63;
  int l0 = GG + qt * 64;
  int tid = threadIdx.x, lane = tid & 63, wid = tid >> 6;

  __shared__ u16 Kl[64][72];
  __shared__ u16 Vtl[64][72];
  __shared__ u16 Pl[4][16][72];

  const u16* Qp  = ws + OFF_Q + (long)b * SS * EE;
  const u16* Kp  = ws + OFF_K + (long)b * SS * EE;
  const u16* Vtp = ws + OFF_VT + (long)(b * HH + h) * DD * SS;

  int qbase = l0 + wid * 16;
  s8v qf[2];
#pragma unroll
  for (int ks = 0; ks < 2; ++ks)
    qf[ks] = *(const s8v*)(Qp + (long)(qbase + (lane & 15)) * EE + h * DD + ks * 32 + (lane >> 4) * 8);

  float m_r[4], l_p[4]; f4v ao[4];
#pragma unroll
  for (int e = 0; e < 4; ++e) { m_r[e] = -1e30f; l_p[e] = 0.f; }
#pragma unroll
  for (int df = 0; df < 4; ++df) ao[df] = f4v{0.f, 0.f, 0.f, 0.f};

  int lo = (l0 - WW > GG) ? (l0 - WW) : GG;
  int hi = (l0 + 64 + WW < SS) ? (l0 + 64 + WW) : SS;
  int ntile = 1 + ((hi - lo) >> 6);

  // staging geometry: each tile = 64x64 bf16 = 512 16B-chunks; thread owns 2 K + 2 V chunks
  const u16* kbase[2]; const u16* vbase[2];
  u16* kdst[2]; u16* vdst[2];
#pragma unroll
  for (int it = 0; it < 2; ++it) {
    int c = tid + it * 256;
    int sr = c >> 3, so = (c & 7) * 8;
    kbase[it] = Kp + (long)sr * EE + h * DD + so;
    vbase[it] = Vtp + (long)sr * SS + so;
    kdst[it] = &Kl[sr][so];
    vdst[it] = &Vtl[sr][so];
  }

  // prologue: stage tile 0 (global keys, kb=0)
  i4v kreg[2], vreg[2];
#pragma unroll
  for (int it = 0; it < 2; ++it) {
    kreg[it] = *(const i4v*)(kbase[it]);
    vreg[it] = *(const i4v*)(vbase[it]);
  }
#pragma unroll
  for (int it = 0; it < 2; ++it) {
    *(i4v*)kdst[it] = kreg[it];
    *(i4v*)vdst[it] = vreg[it];
  }
  __syncthreads();

  for (int t = 0; t < ntile; ++t) {
    int kb = (t == 0) ? 0 : lo + (t - 1) * 64;
    // prefetch next tile into regs (latency hides under compute below)
    if (t + 1 < ntile) {
      int kbn = lo + t * 64;
#pragma unroll
      for (int it = 0; it < 2; ++it) {
        kreg[it] = *(const i4v*)(kbase[it] + (long)kbn * EE);
        vreg[it] = *(const i4v*)(vbase[it] + kbn);
      }
    }

    // QK^T: 16 q-rows x 64 keys per wave
    f4v sc[4];
#pragma unroll
    for (int c = 0; c < 4; ++c) sc[c] = f4v{0.f, 0.f, 0.f, 0.f};
#pragma unroll
    for (int c = 0; c < 4; ++c)
#pragma unroll
      for (int ks = 0; ks < 2; ++ks) {
        s8v kf = *(const s8v*)&Kl[c * 16 + (lane & 15)][ks * 32 + (lane >> 4) * 8];
        sc[c] = MFMA_BF16(qf[ks], kf, sc[c]);
      }

    // window mask: only edge tiles can clip (kb <= l0-256 or kb >= l0+256)
    if (t > 0 && (kb <= l0 - WW || kb >= l0 + WW)) {
#pragma unroll
      for (int c = 0; c < 4; ++c) {
        int key = kb + c * 16 + (lane & 15);
#pragma unroll
        for (int e = 0; e < 4; ++e) {
          int qrow = qbase + (lane >> 4) * 4 + e;
          if (key < qrow - WW || key > qrow + WW) sc[c][e] = -1e30f;
        }
      }
    }

    // defer-max: per-lane tile max; full reduce+rescale only when growth > THR (or t==0)
    float pmax[4];
#pragma unroll
    for (int e = 0; e < 4; ++e)
      pmax[e] = fmaxf(fmaxf(sc[0][e], sc[1][e]), fmaxf(sc[2][e], sc[3][e]));
    bool need;
    if (t == 0) need = true;
    else {
      bool ok = (pmax[0] <= m_r[0] + 8.f) & (pmax[1] <= m_r[1] + 8.f) &
                (pmax[2] <= m_r[2] + 8.f) & (pmax[3] <= m_r[3] + 8.f);
      need = !__all(ok);
    }
    if (need) {
#pragma unroll
      for (int e = 0; e < 4; ++e) {
        float rm = pmax[e];
#pragma unroll
        for (int off = 1; off < 16; off <<= 1) rm = fmaxf(rm, __shfl_xor(rm, off));
        float mn = fmaxf(m_r[e], rm);
        float scl = __expf(m_r[e] - mn);
        l_p[e] *= scl;
#pragma unroll
        for (int df = 0; df < 4; ++df) ao[df][e] *= scl;
        m_r[e] = mn;
      }
    }

    // probabilities + per-lane partial row-sum (no cross-lane reduce here) + P store
#pragma unroll
    for (int e = 0; e < 4; ++e) {
      float p0 = __expf(sc[0][e] - m_r[e]);
      float p1 = __expf(sc[1][e] - m_r[e]);
      float p2 = __expf(sc[2][e] - m_r[e]);
      float p3 = __expf(sc[3][e] - m_r[e]);
      l_p[e] += (p0 + p1) + (p2 + p3);
      int pr = (lane >> 4) * 4 + e;
      Pl[wid][pr][(lane & 15)]      = f2bf(p0);
      Pl[wid][pr][16 + (lane & 15)] = f2bf(p1);
      Pl[wid][pr][32 + (lane & 15)] = f2bf(p2);
      Pl[wid][pr][48 + (lane & 15)] = f2bf(p3);
    }

    // PV: O += P[16x64] * V[64x64]
#pragma unroll
    for (int kblk = 0; kblk < 2; ++kblk) {
      s8v pf = *(const s8v*)&Pl[wid][lane & 15][kblk * 32 + (lane >> 4) * 8];
#pragma unroll
      for (int df = 0; df < 4; ++df) {
        s8v vf = *(const s8v*)&Vtl[df * 16 + (lane & 15)][kblk * 32 + (lane >> 4) * 8];
        ao[df] = MFMA_BF16(pf, vf, ao[df]);
      }
    }
    __syncthreads();   // all waves done reading Kl/Vtl

    if (t + 1 < ntile) {
#pragma unroll
      for (int it = 0; it < 2; ++it) {
        *(i4v*)kdst[it] = kreg[it];
        *(i4v*)vdst[it] = vreg[it];
      }
    }
    __syncthreads();   // staged tile visible
  }

  // final cross-lane row-sum reduce (once), then normalize + store
  float l_r[4];
#pragma unroll
  for (int e = 0; e < 4; ++e) {
    float s = l_p[e];
#pragma unroll
    for (int off = 1; off < 16; off <<= 1) s += __shfl_xor(s, off);
    l_r[e] = s;
  }
#pragma unroll
  for (int df = 0; df < 4; ++df)
#pragma unroll
    for (int e = 0; e < 4; ++e) {
      int row = qbase + (lane >> 4) * 4 + e;
      int col = h * DD + df * 16 + (lane & 15);
      out[((long)b * SS + row) * EE + col] = ao[df][e] / l_r[e];
    }
}

// ---------------- global attention, rows < G: split-K partials ----------------
__global__ __launch_bounds__(64) void k_gattn_part(u16* __restrict__ ws) {
  int bid = blockIdx.x;
  int g = bid / NSPLIT; int sp = bid % NSPLIT;
  int b = g / (HH * 4); int rem = g % (HH * 4); int h = rem >> 2; int qs = rem & 3;
  int lane = threadIdx.x;

  __shared__ u16 Kl[32][72];
  __shared__ u16 Vtl[64][40];
  __shared__ u16 Pl[16][40];

  const u16* Qgp = ws + OFF_QG + (long)b * GG * EE;
  const u16* Kgp = ws + OFF_KG + (long)b * SS * EE;
  const u16* Vtp = ws + OFF_VGT + (long)(b * HH + h) * DD * SS;

  int qbase = qs * 16;
  s8v qf[2];
#pragma unroll
  for (int ks = 0; ks < 2; ++ks)
    qf[ks] = *(const s8v*)(Qgp + (long)(qbase + (lane & 15)) * EE + h * DD + ks * 32 + (lane >> 4) * 8);

  float m_r[4], l_r[4]; f4v ao[4];
#pragma unroll
  for (int e = 0; e < 4; ++e) { m_r[e] = -1e30f; l_r[e] = 0.f; }
#pragma unroll
  for (int df = 0; df < 4; ++df) ao[df] = f4v{0.f, 0.f, 0.f, 0.f};

  int t0 = sp * (SS / 32 / NSPLIT);
  for (int kt = t0; kt < t0 + SS / 32 / NSPLIT; ++kt) {
    int kb = kt * 32;
#pragma unroll
    for (int r2 = 0; r2 < 4; ++r2) {
      int chunk = lane + r2 * 64;
      int kr = chunk >> 3, ko = (chunk & 7) * 8;
      *(i4v*)&Kl[kr][ko] = *(const i4v*)(Kgp + (long)(kb + kr) * EE + h * DD + ko);
      int dr = chunk >> 2, ko2 = (chunk & 3) * 8;
      *(i4v*)&Vtl[dr][ko2] = *(const i4v*)(Vtp + (long)dr * SS + kb + ko2);
    }
    __syncthreads();

    f4v sc[2] = {f4v{0.f, 0.f, 0.f, 0.f}, f4v{0.f, 0.f, 0.f, 0.f}};
#pragma unroll
    for (int c = 0; c < 2; ++c)
#pragma unroll
      for (int ks = 0; ks < 2; ++ks) {
        s8v kf = *(const s8v*)&Kl[c * 16 + (lane & 15)][ks * 32 + (lane >> 4) * 8];
        sc[c] = MFMA_BF16(qf[ks], kf, sc[c]);
      }

    float scl_[4], p0[4], p1[4];
#pragma unroll
    for (int e = 0; e < 4; ++e) {
      float rm = fmaxf(sc[0][e], sc[1][e]);
#pragma unroll
      for (int off = 1; off < 16; off <<= 1) rm = fmaxf(rm, __shfl_xor(rm, off));
      float mn = fmaxf(m_r[e], rm);
      scl_[e] = __expf(m_r[e] - mn);
      p0[e] = __expf(sc[0][e] - mn);
      p1[e] = __expf(sc[1][e] - mn);
      float s = p0[e] + p1[e];
#pragma unroll
      for (int off = 1; off < 16; off <<= 1) s += __shfl_xor(s, off);
      l_r[e] = l_r[e] * scl_[e] + s;
      m_r[e] = mn;
    }
#pragma unroll
    for (int df = 0; df < 4; ++df)
#pragma unroll
      for (int e = 0; e < 4; ++e) ao[df][e] *= scl_[e];

#pragma unroll
    for (int e = 0; e < 4; ++e) {
      Pl[(lane >> 4) * 4 + e][lane & 15]        = f2bf(p0[e]);
      Pl[(lane >> 4) * 4 + e][16 + (lane & 15)] = f2bf(p1[e]);
    }
    s8v pf = *(const s8v*)&Pl[lane & 15][(lane >> 4) * 8];
#pragma unroll
    for (int df = 0; df < 4; ++df) {
      s8v vf = *(const s8v*)&Vtl[df * 16 + (lane & 15)][(lane >> 4) * 8];
      ao[df] = MFMA_BF16(pf, vf, ao[df]);
    }
    __syncthreads();
  }

  float* PA = (float*)(ws + OFF_V);
  float* Pm = PA + NQTILE * NSPLIT * 1024L;
  float* Pl2 = Pm + NQTILE * NSPLIT * 16L;
  long pb = (long)g * NSPLIT + sp;
#pragma unroll
  for (int df = 0; df < 4; ++df)
#pragma unroll
    for (int e = 0; e < 4; ++e) {
      int rl = (lane >> 4) * 4 + e;
      PA[pb * 1024 + rl * 64 + df * 16 + (lane & 15)] = ao[df][e];
    }
  if ((lane & 15) == 0) {
#pragma unroll
    for (int e = 0; e < 4; ++e) {
      int rl = (lane >> 4) * 4 + e;
      Pm[pb * 16 + rl] = m_r[e];
      Pl2[pb * 16 + rl] = l_r[e];
    }
  }
}

// ---------------- global attention: combine partials ----------------
__global__ __launch_bounds__(256) void k_gattn_comb(const u16* __restrict__ ws, float* __restrict__ out) {
  int g = blockIdx.x;
  int b = g / (HH * 4); int rem = g % (HH * 4); int h = rem >> 2; int qs = rem & 3;
  int tid = threadIdx.x;
  int row = tid >> 4; int c4 = (tid & 15) * 4;

  const float* PA = (const float*)(ws + OFF_V);
  const float* Pm = PA + NQTILE * NSPLIT * 1024L;
  const float* Pl2 = Pm + NQTILE * NSPLIT * 16L;
  long base = (long)g * NSPLIT;

  float M = -1e30f;
#pragma unroll
  for (int s = 0; s < NSPLIT; ++s) M = fmaxf(M, Pm[(base + s) * 16 + row]);
  f4v acc = f4v{0.f, 0.f, 0.f, 0.f};
  float L = 0.f;
#pragma unroll
  for (int s = 0; s < NSPLIT; ++s) {
    float wgt = __expf(Pm[(base + s) * 16 + row] - M);
    L += wgt * Pl2[(base + s) * 16 + row];
    f4v a = *(const f4v*)&PA[(base + s) * 1024 + row * 64 + c4];
#pragma unroll
    for (int j = 0; j < 4; ++j) acc[j] += wgt * a[j];
  }
  float inv = 1.f / L;
  f4v o;
#pragma unroll
  for (int j = 0; j < 4; ++j) o[j] = acc[j] * inv;
  *(f4v*)&out[((long)b * SS + qs * 16 + row) * EE + h * DD + c4] = o;
}

extern "C" void kernel_launch(void* const* d_in, const int* in_sizes, int n_in,
                              void* d_out, int out_size, void* d_ws, size_t ws_size,
                              hipStream_t stream) {
  const float* hs  = (const float*)d_in[0];
  const float* Wq  = (const float*)d_in[2];  const float* bq  = (const float*)d_in[3];
  const float* Wk  = (const float*)d_in[4];  const float* bk  = (const float*)d_in[5];
  const float* Wv  = (const float*)d_in[6];  const float* bv  = (const float*)d_in[7];
  const float* Wqg = (const float*)d_in[8];  const float* bqg = (const float*)d_in[9];
  const float* Wkg = (const float*)d_in[10]; const float* bkg = (const float*)d_in[11];
  const float* Wvg = (const float*)d_in[12]; const float* bvg = (const float*)d_in[13];
  u16* ws = (u16*)d_ws;
  float* out = (float*)d_out;

  k_cast<<<(int)(NSE / (256 * 4)), 256, 0, stream>>>(hs, ws + OFF_HSB);
  k_wtrans<<<6 * 24 * 24, 256, 0, stream>>>(Wq, Wk, Wv, Wkg, Wvg, Wqg, ws + OFF_WT);
  k_proj<<<1926, 256, 0, stream>>>(ws, bq, bk, bv, bkg, bvg, bqg);
  k_vtrans<<<2 * 6144, 256, 0, stream>>>(ws);
  k_gattn_part<<<(int)(NQTILE * NSPLIT), 64, 0, stream>>>(ws);
  k_gattn_comb<<<(int)NQTILE, 256, 0, stream>>>(ws, out);
  k_lattn<<<BB * HH * 63, 256, 0, stream>>>(ws, out);
}